// Round 1
// 416.448 us; speedup vs baseline: 1.0389x; 1.0389x over previous
//
#include <hip/hip_runtime.h>
#include <math.h>

// ---------------------------------------------------------------------------
// Decoder step. Inputs all f32 (measured by on-device detector in R2/R4 —
// now hard-coded); outputs f32. bf16 MFMA GEMMs with f32 accumulate.
// Launch graph (7 kernels):
//   setup_k  : ugh-GEMM + xemb-GEMM (f32-staged, run first) overlapped with
//              f32->bf16 conversion of enc/W1/wi/fc1/fc2 (one launch)
//   score_8p : fused score GEMM, 256x256 tile, 8-wave, counted-vmcnt pipeline
//              (T3+T4+T5 per catalog; raw s_barrier, never vmcnt(0) in loop)
//   softmax_f: partial-sum + softmax + context + x_emb pack
//   gemm_f   : gi GEMM ; gru_f ; gemm_f fc1(tanh) ; gemm_f fc2 (f32 out)
// Outputs (concat, f32): out (256x4096) | h_new (256x1024) | attn (256x128)
// ---------------------------------------------------------------------------

#define B_   256
#define L_   128
#define V_   4096
#define ENC_ 1024
#define DEC_ 1024
#define EMB_ 512
#define MB_  1048576ull

typedef __bf16 bf16;
typedef __bf16 bf16x8 __attribute__((ext_vector_type(8)));
typedef __bf16 bf16x4 __attribute__((ext_vector_type(4)));
typedef float  f32x4  __attribute__((ext_vector_type(4)));

__device__ __forceinline__ float fast_tanh(float x) {
  float e = __builtin_amdgcn_exp2f(x * 2.88539008177792681472f);
  return 1.0f - 2.0f * __builtin_amdgcn_rcpf(e + 1.0f);
}
__device__ __forceinline__ float fast_sigmoid(float x) {
  return __builtin_amdgcn_rcpf(1.0f + __builtin_amdgcn_exp2f(-1.44269504088896f * x));
}

// async 16B global->LDS copy
__device__ __forceinline__ void cp16(const void* g, void* l) {
  __builtin_amdgcn_global_load_lds(
      (const __attribute__((address_space(1))) void*)g,
      (__attribute__((address_space(3))) void*)l,
      16, 0, 0);
}

// 8 f32 -> bf16x8
__device__ __forceinline__ bf16x8 ld8f(const float* f) {
  f32x4 a = *(const f32x4*)f;
  f32x4 b = *(const f32x4*)(f + 4);
  bf16x8 r;
  r[0] = (bf16)a[0]; r[1] = (bf16)a[1]; r[2] = (bf16)a[2]; r[3] = (bf16)a[3];
  r[4] = (bf16)b[0]; r[5] = (bf16)b[1]; r[6] = (bf16)b[2]; r[7] = (bf16)b[3];
  return r;
}

// ---------------------------------------------------------------------------
// LDS XOR swizzle (R5-verified, 0 bank conflicts):
// tile slot (r, lb) [lb = 16B block 0..7] holds global cols
// k0 + ((lb ^ (r&7))*8 .. +8). Fragment read for (row ra, k-quad kq):
// offset = ra*64 + ((kq ^ (ra&7))<<3).
// ---------------------------------------------------------------------------

// 64x64-tile GEMM inner loop, f32 inputs staged manually with swizzle.
__device__ __forceinline__ void gemm64_f32(
    const float* __restrict__ A, const float* __restrict__ Brow,
    int strideA, int strideB, int kbeg, int kend, int row0,
    bf16* As, bf16* Bs, f32x4 acc[4])
{
  const int t   = threadIdx.x;
  const int lane = t & 63, w = t >> 6, q = lane >> 4, c16 = lane & 15;
  const int sr  = t >> 3, lb = t & 7;

  for (int k0 = kbeg; k0 < kend; k0 += 64) {
    bf16x8 va[2], vb[2];
#pragma unroll
    for (int ch = 0; ch < 2; ch++) {
      int r    = ch * 32 + sr;
      int gcol = k0 + ((lb ^ (r & 7)) << 3);
      va[ch] = ld8f(A    + (size_t)(row0 + r) * strideA + gcol);
      vb[ch] = ld8f(Brow + (size_t)r * strideB + gcol);
    }
#pragma unroll
    for (int ch = 0; ch < 2; ch++) {
      *(bf16x8*)&As[ch * 2048 + t * 8] = va[ch];
      *(bf16x8*)&Bs[ch * 2048 + t * 8] = vb[ch];
    }
    __syncthreads();
#pragma unroll
    for (int kkb = 0; kkb < 8; kkb += 4) {
      int rb = w * 16 + c16;
      bf16x8 bfr = *(const bf16x8*)&Bs[rb * 64 + (((kkb + q) ^ (rb & 7)) << 3)];
#pragma unroll
      for (int i = 0; i < 4; i++) {
        int ra = i * 16 + c16;
        bf16x8 af = *(const bf16x8*)&As[ra * 64 + (((kkb + q) ^ (ra & 7)) << 3)];
        acc[i] = __builtin_amdgcn_mfma_f32_16x16x32_bf16(af, bfr, acc[i], 0, 0, 0);
      }
    }
    __syncthreads();
  }
}

// ---------------------------------------------------------------------------
// setup_k: role-switched mega-launch.
//   blocks [0,256)      : ugh GEMM  (u | gh from h0)  — latency-bound, first
//   blocks [256,384)    : xemb GEMM (split-K 4)
//   blocks [384,10624)  : f32->bf16 conversion (enc, W1, wi, fc1, fc2)
// ---------------------------------------------------------------------------
__global__ __launch_bounds__(256) void setup_k(
    const float* __restrict__ hidden, const float* __restrict__ W2,
    const float* __restrict__ wh, const float* __restrict__ W1_b,
    const float* __restrict__ W2_b, const float* __restrict__ gbh,
    const float* __restrict__ x, const float* __restrict__ o2e,
    const float* __restrict__ enc, const float* __restrict__ W1,
    const float* __restrict__ wi, const float* __restrict__ fc1w,
    const float* __restrict__ fc2w,
    bf16* __restrict__ enc_bf, bf16* __restrict__ W1_bf,
    bf16* __restrict__ wi_bf, bf16* __restrict__ fc1_bf,
    bf16* __restrict__ fc2_bf,
    bf16* __restrict__ u, bf16* __restrict__ gh, float* __restrict__ xe4)
{
  __shared__ __align__(16) bf16 As[64 * 64];
  __shared__ __align__(16) bf16 Bs[64 * 64];

  const int bid = blockIdx.x;
  const int t   = threadIdx.x;

  if (bid >= 384) {
    // -------- conversion role --------
    int i = bid - 384;
    const float* src; bf16* dst; int blk;
    if      (i < 8192) { src = enc;  dst = enc_bf; blk = i; }
    else if (i < 8448) { src = W1;   dst = W1_bf;  blk = i - 8192; }
    else if (i < 9600) { src = wi;   dst = wi_bf;  blk = i - 8448; }
    else if (i < 9728) { src = fc1w; dst = fc1_bf; blk = i - 9600; }
    else               { src = fc2w; dst = fc2_bf; blk = i - 9728; }
    const size_t base = (size_t)blk * 4096 + t * 16;
    const float* s = src + base;
    bf16* d = dst + base;
    *(bf16x8*)(d)     = ld8f(s);
    *(bf16x8*)(d + 8) = ld8f(s + 8);
    return;
  }

  const int lane = t & 63, w = t >> 6, q = lane >> 4, c16 = lane & 15;
  f32x4 acc[4] = {};

  if (bid < 256) {
    // -------- ugh role: cols [0,1024)->u (W2, +W1_b+W2_b); rest->gh --------
    const int row0 = (bid >> 6) * 64;
    const int col0 = (bid & 63) * 64;
    const bool isU = (col0 < 1024);
    const float* Brow = isU ? (W2 + (size_t)col0 * 1024)
                            : (wh + (size_t)(col0 - 1024) * 1024);
    gemm64_f32(hidden, Brow, 1024, 1024, 0, 1024, row0, As, Bs, acc);

    const int gc = col0 + w * 16 + c16;
    float bias = isU ? (W1_b[gc] + W2_b[gc]) : gbh[gc - 1024];
#pragma unroll
    for (int i = 0; i < 4; i++) {
      int gr0 = row0 + i * 16 + q * 4;
#pragma unroll
      for (int r = 0; r < 4; r++) {
        float v = acc[i][r] + bias;
        if (isU) u[(size_t)(gr0 + r) * 1024 + gc] = (bf16)v;
        else     gh[(size_t)(gr0 + r) * 3072 + (gc - 1024)] = (bf16)v;
      }
    }
  } else {
    // -------- xemb role: xe4[z] = x @ o2e^T over K slab z --------
    const int i3   = bid - 256;
    const int col0 = (i3 & 7) * 64;
    const int row0 = ((i3 >> 3) & 3) * 64;
    const int z    = i3 >> 5;
    gemm64_f32(x, o2e + (size_t)col0 * 4096, 4096, 4096,
               z * 1024, z * 1024 + 1024, row0, As, Bs, acc);

    const int gc = col0 + w * 16 + c16;
    float* out = xe4 + (size_t)z * 131072;
#pragma unroll
    for (int i = 0; i < 4; i++) {
      int gr0 = row0 + i * 16 + q * 4;
#pragma unroll
      for (int r = 0; r < 4; r++)
        out[(size_t)(gr0 + r) * 512 + gc] = acc[i][r];
    }
  }
}

// ---------------------------------------------------------------------------
// score_8p: e_part[bx][row] = sum_{d in col-group bx} tanh(enc·W1 + u)*Vw
// 256x256 tile, BK=64, 512 threads (8 waves, 2M x 4N, 128x64 per wave).
// Counted-vmcnt double-buffer pipeline (T3+T4), raw s_barrier (no drain),
// setprio around the MFMA cluster (T5). LDS 128KB + 4KB reduce buffer,
// 1 block/CU. Stage K-tile kt+2 into the buffer freed at barrier 1 of
// iteration kt; vmcnt(8) leaves those 8 loads in flight, guarantees kt+1.
// grid = 512 linear blocks, XCD-chunked bijective remap (512 % 8 == 0).
// ---------------------------------------------------------------------------
__device__ __forceinline__ void stage_tile256(
    const bf16* __restrict__ A, const bf16* __restrict__ Bw,
    bf16* As, bf16* Bs, int row0, int col0, int k0, int t)
{
  const int sr = t >> 3, lb = t & 7;
#pragma unroll
  for (int ch = 0; ch < 4; ch++) {
    int r    = ch * 64 + sr;
    int gcol = k0 + ((lb ^ (r & 7)) << 3);
    cp16(A  + (size_t)(row0 + r) * 1024 + gcol, &As[r * 64 + lb * 8]);
    cp16(Bw + (size_t)(col0 + r) * 1024 + gcol, &Bs[r * 64 + lb * 8]);
  }
}

__global__ __launch_bounds__(512, 2) void score_8p(
    const bf16* __restrict__ A,    // enc_bf (32768 x 1024)
    const bf16* __restrict__ Bw,   // W1_bf (1024 x 1024)
    const bf16* __restrict__ u,    // (256 x 1024) bf16
    const float* __restrict__ Vw,  // (1024) f32
    float* __restrict__ e_part)    // (4 x 32768)
{
  __shared__ __align__(16) bf16 sA[2 * 16384];   // 64 KB (2 bufs x 256x64)
  __shared__ __align__(16) bf16 sB[2 * 16384];   // 64 KB
  __shared__ float s_part[4][256];               // 4 KB

  const int t = threadIdx.x;
  // XCD-chunked remap: 4 col-group blocks sharing an enc slab -> same XCD
  const int wg  = blockIdx.x;
  const int swz = (wg & 7) * 64 + (wg >> 3);
  const int bx  = swz & 3;
  const int by  = swz >> 2;
  const int row0 = by * 256;
  const int col0 = bx * 256;

  const int lane = t & 63, w = t >> 6;
  const int wm = w >> 2, wn = w & 3;          // 2M x 4N wave grid
  const int q = lane >> 4, c16 = lane & 15;

  // prologue: K-tiles 0 -> buf0, 1 -> buf1; wait only tile 0 (8 newest stay)
  stage_tile256(A, Bw, sA, sB, row0, col0, 0, t);
  stage_tile256(A, Bw, sA + 16384, sB + 16384, row0, col0, 64, t);
  asm volatile("s_waitcnt vmcnt(8)" ::: "memory");
  __builtin_amdgcn_s_barrier();

  f32x4 acc[8][4] = {};

  for (int kt = 0; kt < 16; ++kt) {
    const bf16* As = sA + (kt & 1) * 16384;
    const bf16* Bs = sB + (kt & 1) * 16384;

    bf16x8 bfr[2][4];
#pragma unroll
    for (int j = 0; j < 4; j++) {
      const int rb = wn * 64 + j * 16 + c16;
      bfr[0][j] = *(const bf16x8*)&Bs[rb * 64 + (((0 + q) ^ (rb & 7)) << 3)];
      bfr[1][j] = *(const bf16x8*)&Bs[rb * 64 + (((4 + q) ^ (rb & 7)) << 3)];
    }
    __builtin_amdgcn_s_setprio(1);
#pragma unroll
    for (int i = 0; i < 8; i++) {
      const int ra = wm * 128 + i * 16 + c16;
      bf16x8 a0 = *(const bf16x8*)&As[ra * 64 + (((0 + q) ^ (ra & 7)) << 3)];
      bf16x8 a1 = *(const bf16x8*)&As[ra * 64 + (((4 + q) ^ (ra & 7)) << 3)];
#pragma unroll
      for (int j = 0; j < 4; j++)
        acc[i][j] = __builtin_amdgcn_mfma_f32_16x16x32_bf16(a0, bfr[0][j], acc[i][j], 0, 0, 0);
#pragma unroll
      for (int j = 0; j < 4; j++)
        acc[i][j] = __builtin_amdgcn_mfma_f32_16x16x32_bf16(a1, bfr[1][j], acc[i][j], 0, 0, 0);
    }
    __builtin_amdgcn_s_setprio(0);
    // barrier 1: every wave consumed buf[kt&1] (MFMA deps forced lgkmcnt)
    __builtin_amdgcn_s_barrier();
    if (kt < 14) {
      stage_tile256(A, Bw, sA + (kt & 1) * 16384, sB + (kt & 1) * 16384,
                    row0, col0, (kt + 2) * 64, t);
      // counted wait: drains K-tile kt+1's 8 loads, keeps kt+2's 8 in flight
      asm volatile("s_waitcnt vmcnt(8)" ::: "memory");
    } else {
      asm volatile("s_waitcnt vmcnt(0)" ::: "memory");
    }
    // barrier 2: collectively, next buffer is ready
    __builtin_amdgcn_s_barrier();
  }

  // epilogue: rowsum_j tanh(acc + u[b])*Vw, reduce 16 lanes, then 4 wn-waves
  const int b = by * 2 + wm;
  float uc[4], vw[4];
#pragma unroll
  for (int j = 0; j < 4; j++) {
    const int gc = col0 + wn * 64 + j * 16 + c16;
    uc[j] = (float)u[b * 1024 + gc];
    vw[j] = Vw[gc];
  }
#pragma unroll
  for (int i = 0; i < 8; i++) {
#pragma unroll
    for (int r = 0; r < 4; r++) {
      float v = 0.0f;
#pragma unroll
      for (int j = 0; j < 4; j++)
        v += fast_tanh(acc[i][j][r] + uc[j]) * vw[j];
      v += __shfl_xor(v, 1);
      v += __shfl_xor(v, 2);
      v += __shfl_xor(v, 4);
      v += __shfl_xor(v, 8);
      if (c16 == 0) s_part[wn][wm * 128 + i * 16 + q * 4 + r] = v;
    }
  }
  __syncthreads();
  if (t < 256)
    e_part[(size_t)bx * 32768 + row0 + t] =
        s_part[0][t] + s_part[1][t] + s_part[2][t] + s_part[3][t];
}

// ---------------------------------------------------------------------------
// softmax + context + x_emb pack. grid 256 (one per b).
// ---------------------------------------------------------------------------
__global__ __launch_bounds__(256) void softmax_f(
    const float* __restrict__ e_part, // (4, 32768)
    const bf16* __restrict__ enc,     // enc_bf
    const float* __restrict__ xe4,    // (4,256,512)
    const float* __restrict__ o2eb,   // (512)
    float* __restrict__ attn_out,     // -> d_out section 3
    bf16* __restrict__ rnn_in)        // (256,1536)
{
  const int b = blockIdx.x;
  const int t = threadIdx.x;
  __shared__ float se[128];

  if (t < 128) {
    float s = 0.0f;
#pragma unroll
    for (int cb = 0; cb < 4; cb++) s += e_part[(size_t)cb * 32768 + b * 128 + t];
    se[t] = s;
  }
  __syncthreads();

  float m = -1e30f;
  for (int l = 0; l < 128; l++) m = fmaxf(m, se[l]);
  float sum = 0.0f;
  for (int l = 0; l < 128; l++) sum += expf(se[l] - m);
  float inv = 1.0f / sum;
  __syncthreads();
  if (t < 128) {
    float p = expf(se[t] - m) * inv;
    attn_out[b * 128 + t] = p;
    se[t] = p;
  }
  __syncthreads();

  // context: thread t handles 4 contiguous k of 1024
  float a0 = 0, a1 = 0, a2 = 0, a3 = 0;
  const bf16* ep = enc + (size_t)b * L_ * ENC_ + t * 4;
  for (int l = 0; l < 128; l++) {
    float p = se[l];
    bf16x4 v = *(const bf16x4*)(ep + (size_t)l * ENC_);
    a0 += p * (float)v[0]; a1 += p * (float)v[1];
    a2 += p * (float)v[2]; a3 += p * (float)v[3];
  }
  bf16x4 o;
  o[0] = (bf16)a0; o[1] = (bf16)a1; o[2] = (bf16)a2; o[3] = (bf16)a3;
  *(bf16x4*)(rnn_in + (size_t)b * 1536 + t * 4) = o;

  // x_emb pack: rnn_in[b][1024+j] = sum_z xe4[z][b][j] + o2e_b[j]
#pragma unroll
  for (int jj = 0; jj < 2; jj++) {
    int j = jj * 256 + t;
    float v = o2eb[j];
#pragma unroll
    for (int z = 0; z < 4; z++) v += xe4[(size_t)z * 131072 + b * 512 + j];
    rnn_in[(size_t)b * 1536 + 1024 + j] = (bf16)v;
  }
}

// ---------------------------------------------------------------------------
// Generic bf16 skinny GEMM (global_load_lds + swizzle). 64x64 tile, BK=64.
// ---------------------------------------------------------------------------
template <int ACT, int OUTF32>
__global__ __launch_bounds__(256) void gemm_f(
    const bf16* __restrict__ A, const bf16* __restrict__ Bw,
    const float* __restrict__ bias1,
    void* __restrict__ C, int K, int out_ld)
{
  __shared__ __align__(16) bf16 As[64 * 64];
  __shared__ __align__(16) bf16 Bs[64 * 64];

  const int t    = threadIdx.x;
  const int lane = t & 63;
  const int w    = t >> 6;
  const int q    = lane >> 4;
  const int c16  = lane & 15;
  const int sr   = t >> 3;
  const int lb   = t & 7;
  const int row0 = blockIdx.y * 64;
  const int col0 = blockIdx.x * 64;

  f32x4 acc[4] = {};

  for (int k0 = 0; k0 < K; k0 += 64) {
#pragma unroll
    for (int ch = 0; ch < 2; ch++) {
      int r    = ch * 32 + sr;
      int gcol = k0 + ((lb ^ (r & 7)) << 3);
      cp16(A  + (size_t)(row0 + r) * K + gcol, &As[ch * 2048 + t * 8]);
      cp16(Bw + (size_t)(col0 + r) * K + gcol, &Bs[ch * 2048 + t * 8]);
    }
    __syncthreads();
#pragma unroll
    for (int kkb = 0; kkb < 8; kkb += 4) {
      int rb = w * 16 + c16;
      bf16x8 bfr = *(const bf16x8*)&Bs[rb * 64 + (((kkb + q) ^ (rb & 7)) << 3)];
#pragma unroll
      for (int i = 0; i < 4; i++) {
        int ra = i * 16 + c16;
        bf16x8 af = *(const bf16x8*)&As[ra * 64 + (((kkb + q) ^ (ra & 7)) << 3)];
        acc[i] = __builtin_amdgcn_mfma_f32_16x16x32_bf16(af, bfr, acc[i], 0, 0, 0);
      }
    }
    __syncthreads();
  }

  const int gc = col0 + w * 16 + c16;
  float bias = bias1[gc];
#pragma unroll
  for (int i = 0; i < 4; i++) {
    int gr0 = row0 + i * 16 + q * 4;
#pragma unroll
    for (int r = 0; r < 4; r++) {
      float v = acc[i][r] + bias;
      if (ACT == 1) v = fast_tanh(v);
      size_t off = (size_t)(gr0 + r) * out_ld + gc;
      if (OUTF32) ((float*)C)[off] = v;
      else        ((bf16*)C)[off] = (bf16)v;
    }
  }
}

// ---------------------------------------------------------------------------
// GRU gates. 262144 threads. h0 f32 external.
// ---------------------------------------------------------------------------
__global__ __launch_bounds__(256) void gru_f(
    const bf16* __restrict__ gi, const bf16* __restrict__ gh,
    const float* __restrict__ h0,
    float* __restrict__ hnew_out, bf16* __restrict__ hnew_i)
{
  int idx = blockIdx.x * 256 + threadIdx.x;
  int b = idx >> 10, d = idx & 1023;
  const bf16* gib = gi + b * 3072;
  const bf16* ghb = gh + b * 3072;
  float ir = (float)gib[d], iz = (float)gib[1024 + d], in = (float)gib[2048 + d];
  float hr = (float)ghb[d], hz = (float)ghb[1024 + d], hn = (float)ghb[2048 + d];
  float r = fast_sigmoid(ir + hr);
  float z = fast_sigmoid(iz + hz);
  float n = fast_tanh(in + r * hn);
  float h = (1.0f - z) * n + z * h0[idx];
  hnew_out[idx] = h;
  hnew_i[idx]   = (bf16)h;
}

// ---------------------------------------------------------------------------
extern "C" void kernel_launch(void* const* d_in, const int* in_sizes, int n_in,
                              void* d_out, int out_size, void* d_ws, size_t ws_size,
                              hipStream_t stream) {
  const float* x      = (const float*)d_in[0];
  const float* hidden = (const float*)d_in[1];
  const float* enc    = (const float*)d_in[2];
  const float* W1_w   = (const float*)d_in[3];
  const float* W1_b   = (const float*)d_in[4];
  const float* W2_w   = (const float*)d_in[5];
  const float* W2_b   = (const float*)d_in[6];
  const float* V_w    = (const float*)d_in[7];
  // d_in[8] = V_b : softmax-invariant, unused
  const float* o2e_w  = (const float*)d_in[9];
  const float* o2e_b  = (const float*)d_in[10];
  const float* gru_wi = (const float*)d_in[11];
  const float* gru_wh = (const float*)d_in[12];
  const float* gru_bi = (const float*)d_in[13];
  const float* gru_bh = (const float*)d_in[14];
  const float* fc1_w  = (const float*)d_in[15];
  const float* fc1_b  = (const float*)d_in[16];
  const float* fc2_w  = (const float*)d_in[17];
  const float* fc2_b  = (const float*)d_in[18];

  float* out_main = (float*)d_out;                      // (256,4096)
  float* out_h    = out_main + (size_t)B_ * V_;         // (256,1024)
  float* out_attn = out_h + (size_t)B_ * DEC_;          // (256,128)

  // ws layout (bytes); NEED ~88 MB (ws_size >= ~103 MB measured in R5)
  char* ws = (char*)d_ws;
  bf16*  enc_bf  = (bf16*)(ws);                    // 64 MB
  bf16*  W1_bf   = (bf16*)(ws + 64 * MB_);         // 2 MB
  bf16*  wi_bf   = (bf16*)(ws + 66 * MB_);         // 9 MB
  bf16*  fc1_bf  = (bf16*)(ws + 75 * MB_);         // 1 MB
  bf16*  fc2_bf  = (bf16*)(ws + 76 * MB_);         // 4 MB
  bf16*  u_bf    = (bf16*)(ws + 80 * MB_);         // 512 KB
  bf16*  gh_bf   = (bf16*)(ws + 80 * MB_ + 524288);      // 1.5 MB
  float* e_part  = (float*)(ws + 82 * MB_);              // 512 KB
  bf16*  gi_bf   = (bf16*)(ws + 82 * MB_ + 524288);      // 1.5 MB
  bf16*  rnn_in  = (bf16*)(ws + 84 * MB_);               // 768 KB
  bf16*  tbuf    = (bf16*)(ws + 84 * MB_ + 786432);      // 256 KB
  bf16*  hnew_bf = (bf16*)(ws + 85 * MB_);               // 512 KB
  float* xe4     = (float*)(ws + 85 * MB_ + 524288);     // 2 MB

  // 1. setup: ugh + xemb GEMMs (blocks 0..383) overlapped with conversions
  setup_k<<<10624, 256, 0, stream>>>(
      hidden, W2_w, gru_wh, W1_b, W2_b, gru_bh, x, o2e_w,
      enc, W1_w, gru_wi, fc1_w, fc2_w,
      enc_bf, W1_bf, wi_bf, fc1_bf, fc2_bf, u_bf, gh_bf, xe4);

  // 2. score GEMM (256x256 tile, counted-vmcnt pipeline) -> e_part
  score_8p<<<512, 512, 0, stream>>>(enc_bf, W1_bf, u_bf, V_w, e_part);

  // 3. softmax + context + x_emb pack
  softmax_f<<<B_, 256, 0, stream>>>(e_part, enc_bf, xe4, o2e_b, out_attn, rnn_in);

  // 4. gi = rnn_in @ wi^T + gru_bi (256x3072, K=1536)
  gemm_f<0, 0><<<dim3(48, 4), 256, 0, stream>>>(rnn_in, wi_bf, gru_bi, gi_bf, 1536, 3072);

  // 5. GRU gates -> h_new
  gru_f<<<(B_ * DEC_) / 256, 256, 0, stream>>>(gi_bf, gh_bf, hidden, out_h, hnew_bf);

  // 6. t = tanh(h_new @ fc1^T + fc1_b) (256x512, K=1024)
  gemm_f<1, 0><<<dim3(8, 4), 256, 0, stream>>>(hnew_bf, fc1_bf, fc1_b, tbuf, 1024, 512);

  // 7. out = t @ fc2^T + fc2_b (256x4096, K=512, f32 out)
  gemm_f<0, 1><<<dim3(64, 4), 256, 0, stream>>>(tbuf, fc2_bf, fc2_b, out_main, 512, 4096);
}

// Round 2
// 407.459 us; speedup vs baseline: 1.0619x; 1.0221x over previous
//
#include <hip/hip_runtime.h>
#include <math.h>

// ---------------------------------------------------------------------------
// Decoder step. Inputs all f32 (measured by on-device detector in R2/R4 —
// now hard-coded); outputs f32. bf16 MFMA GEMMs with f32 accumulate.
// Launch graph (7 kernels):
//   setup_k  : ugh-GEMM + xemb-GEMM (f32-staged, run first) overlapped with
//              f32->bf16 conversion of enc/W1/wi/fc1/fc2 (one launch)
//   score_8p : fused score GEMM, 256x256 tile, TRUE 4-phase/K-tile m201-style
//              interleave: per phase {ds_read frag ; stage 1 half-tile ;
//              barrier ; lgkmcnt(0) ; 16 MFMA ; barrier}, single counted
//              vmcnt(4) per K-tile (derived-wait proof in comments).
//   softmax_f: partial-sum + softmax + context + x_emb pack
//   gemm_f   : gi GEMM ; gru_f ; gemm_f fc1(tanh) ; gemm_f fc2 (f32 out)
// Outputs (concat, f32): out (256x4096) | h_new (256x1024) | attn (256x128)
// ---------------------------------------------------------------------------

#define B_   256
#define L_   128
#define V_   4096
#define ENC_ 1024
#define DEC_ 1024
#define EMB_ 512
#define MB_  1048576ull

typedef __bf16 bf16;
typedef __bf16 bf16x8 __attribute__((ext_vector_type(8)));
typedef __bf16 bf16x4 __attribute__((ext_vector_type(4)));
typedef float  f32x4  __attribute__((ext_vector_type(4)));

__device__ __forceinline__ float fast_tanh(float x) {
  float e = __builtin_amdgcn_exp2f(x * 2.88539008177792681472f);
  return 1.0f - 2.0f * __builtin_amdgcn_rcpf(e + 1.0f);
}
__device__ __forceinline__ float fast_sigmoid(float x) {
  return __builtin_amdgcn_rcpf(1.0f + __builtin_amdgcn_exp2f(-1.44269504088896f * x));
}

// async 16B global->LDS copy
__device__ __forceinline__ void cp16(const void* g, void* l) {
  __builtin_amdgcn_global_load_lds(
      (const __attribute__((address_space(1))) void*)g,
      (__attribute__((address_space(3))) void*)l,
      16, 0, 0);
}

// 8 f32 -> bf16x8
__device__ __forceinline__ bf16x8 ld8f(const float* f) {
  f32x4 a = *(const f32x4*)f;
  f32x4 b = *(const f32x4*)(f + 4);
  bf16x8 r;
  r[0] = (bf16)a[0]; r[1] = (bf16)a[1]; r[2] = (bf16)a[2]; r[3] = (bf16)a[3];
  r[4] = (bf16)b[0]; r[5] = (bf16)b[1]; r[6] = (bf16)b[2]; r[7] = (bf16)b[3];
  return r;
}

// ---------------------------------------------------------------------------
// LDS XOR swizzle (R5-verified, 0 bank conflicts):
// tile slot (r, lb) [lb = 16B block 0..7] holds global cols
// k0 + ((lb ^ (r&7))*8 .. +8). Fragment read for (row ra, k-quad kq):
// offset = ra*64 + ((kq ^ (ra&7))<<3).
// ---------------------------------------------------------------------------

// 64x64-tile GEMM inner loop, f32 inputs staged manually with swizzle.
__device__ __forceinline__ void gemm64_f32(
    const float* __restrict__ A, const float* __restrict__ Brow,
    int strideA, int strideB, int kbeg, int kend, int row0,
    bf16* As, bf16* Bs, f32x4 acc[4])
{
  const int t   = threadIdx.x;
  const int lane = t & 63, w = t >> 6, q = lane >> 4, c16 = lane & 15;
  const int sr  = t >> 3, lb = t & 7;

  for (int k0 = kbeg; k0 < kend; k0 += 64) {
    bf16x8 va[2], vb[2];
#pragma unroll
    for (int ch = 0; ch < 2; ch++) {
      int r    = ch * 32 + sr;
      int gcol = k0 + ((lb ^ (r & 7)) << 3);
      va[ch] = ld8f(A    + (size_t)(row0 + r) * strideA + gcol);
      vb[ch] = ld8f(Brow + (size_t)r * strideB + gcol);
    }
#pragma unroll
    for (int ch = 0; ch < 2; ch++) {
      *(bf16x8*)&As[ch * 2048 + t * 8] = va[ch];
      *(bf16x8*)&Bs[ch * 2048 + t * 8] = vb[ch];
    }
    __syncthreads();
#pragma unroll
    for (int kkb = 0; kkb < 8; kkb += 4) {
      int rb = w * 16 + c16;
      bf16x8 bfr = *(const bf16x8*)&Bs[rb * 64 + (((kkb + q) ^ (rb & 7)) << 3)];
#pragma unroll
      for (int i = 0; i < 4; i++) {
        int ra = i * 16 + c16;
        bf16x8 af = *(const bf16x8*)&As[ra * 64 + (((kkb + q) ^ (ra & 7)) << 3)];
        acc[i] = __builtin_amdgcn_mfma_f32_16x16x32_bf16(af, bfr, acc[i], 0, 0, 0);
      }
    }
    __syncthreads();
  }
}

// ---------------------------------------------------------------------------
// setup_k: role-switched mega-launch.
//   blocks [0,256)      : ugh GEMM  (u | gh from h0)  — latency-bound, first
//   blocks [256,384)    : xemb GEMM (split-K 4)
//   blocks [384,10624)  : f32->bf16 conversion (enc, W1, wi, fc1, fc2)
// ---------------------------------------------------------------------------
__global__ __launch_bounds__(256) void setup_k(
    const float* __restrict__ hidden, const float* __restrict__ W2,
    const float* __restrict__ wh, const float* __restrict__ W1_b,
    const float* __restrict__ W2_b, const float* __restrict__ gbh,
    const float* __restrict__ x, const float* __restrict__ o2e,
    const float* __restrict__ enc, const float* __restrict__ W1,
    const float* __restrict__ wi, const float* __restrict__ fc1w,
    const float* __restrict__ fc2w,
    bf16* __restrict__ enc_bf, bf16* __restrict__ W1_bf,
    bf16* __restrict__ wi_bf, bf16* __restrict__ fc1_bf,
    bf16* __restrict__ fc2_bf,
    bf16* __restrict__ u, bf16* __restrict__ gh, float* __restrict__ xe4)
{
  __shared__ __align__(16) bf16 As[64 * 64];
  __shared__ __align__(16) bf16 Bs[64 * 64];

  const int bid = blockIdx.x;
  const int t   = threadIdx.x;

  if (bid >= 384) {
    // -------- conversion role --------
    int i = bid - 384;
    const float* src; bf16* dst; int blk;
    if      (i < 8192) { src = enc;  dst = enc_bf; blk = i; }
    else if (i < 8448) { src = W1;   dst = W1_bf;  blk = i - 8192; }
    else if (i < 9600) { src = wi;   dst = wi_bf;  blk = i - 8448; }
    else if (i < 9728) { src = fc1w; dst = fc1_bf; blk = i - 9600; }
    else               { src = fc2w; dst = fc2_bf; blk = i - 9728; }
    const size_t base = (size_t)blk * 4096 + t * 16;
    const float* s = src + base;
    bf16* d = dst + base;
    *(bf16x8*)(d)     = ld8f(s);
    *(bf16x8*)(d + 8) = ld8f(s + 8);
    return;
  }

  const int lane = t & 63, w = t >> 6, q = lane >> 4, c16 = lane & 15;
  f32x4 acc[4] = {};

  if (bid < 256) {
    // -------- ugh role: cols [0,1024)->u (W2, +W1_b+W2_b); rest->gh --------
    const int row0 = (bid >> 6) * 64;
    const int col0 = (bid & 63) * 64;
    const bool isU = (col0 < 1024);
    const float* Brow = isU ? (W2 + (size_t)col0 * 1024)
                            : (wh + (size_t)(col0 - 1024) * 1024);
    gemm64_f32(hidden, Brow, 1024, 1024, 0, 1024, row0, As, Bs, acc);

    const int gc = col0 + w * 16 + c16;
    float bias = isU ? (W1_b[gc] + W2_b[gc]) : gbh[gc - 1024];
#pragma unroll
    for (int i = 0; i < 4; i++) {
      int gr0 = row0 + i * 16 + q * 4;
#pragma unroll
      for (int r = 0; r < 4; r++) {
        float v = acc[i][r] + bias;
        if (isU) u[(size_t)(gr0 + r) * 1024 + gc] = (bf16)v;
        else     gh[(size_t)(gr0 + r) * 3072 + (gc - 1024)] = (bf16)v;
      }
    }
  } else {
    // -------- xemb role: xe4[z] = x @ o2e^T over K slab z --------
    const int i3   = bid - 256;
    const int col0 = (i3 & 7) * 64;
    const int row0 = ((i3 >> 3) & 3) * 64;
    const int z    = i3 >> 5;
    gemm64_f32(x, o2e + (size_t)col0 * 4096, 4096, 4096,
               z * 1024, z * 1024 + 1024, row0, As, Bs, acc);

    const int gc = col0 + w * 16 + c16;
    float* out = xe4 + (size_t)z * 131072;
#pragma unroll
    for (int i = 0; i < 4; i++) {
      int gr0 = row0 + i * 16 + q * 4;
#pragma unroll
      for (int r = 0; r < 4; r++)
        out[(size_t)(gr0 + r) * 512 + gc] = acc[i][r];
    }
  }
}

// ---------------------------------------------------------------------------
// score_8p: e_part[bx][row] = sum_{d in col-group bx} tanh(enc·W1 + u)*Vw
// 256x256 tile, BK=64, 512 threads (8 waves, 2M x 4N, 128x64 per wave).
// TRUE 4-phase/K-tile interleaved schedule (m201 port, derived waits):
//   P1: read a(i0-3,kh0)+b(j,kh0) | stage A(kt+1)h0 | bar;lgkm0 | 16 MFMA | bar
//   P2: read a(i0-3,kh1)+b(j,kh1) | stage A(kt+1)h1 | ...       | 16 MFMA | bar
//   P3: read a(i4-7,kh0) [b kh0 reused in regs] | stage B(kt+2)h0 | 16 MFMA
//   P4: read a(i4-7,kh1) [b kh1 reused]         | stage B(kt+2)h1 | 16 MFMA
//       then vmcnt(4) (leaves only B(kt+2)'s 2 half-tiles in flight,
//       guarantees all of tile kt+1) ; bar.
// Hazard proof:
//  - A-buf[1-cur] overwrite (P1/P2 of kt) is after P4-of-(kt-1) barrier-2,
//    which postdates every wave's lgkmcnt(0)-completed reads of tile kt-1.
//  - B-buf[cur] overwrite (P3/P4 of kt) is after P2-of-kt barrier-2; all B
//    reads of tile kt happen at P1/P2 and complete at those phases' lgkm0.
//  - Reads of tile kt are collectively guaranteed by the vmcnt(4)+barrier at
//    P4 of kt-1 (outstanding there = B(kt+1)'s 4 loads only).
// grid = 512 linear blocks, XCD-chunked bijective remap (512 % 8 == 0).
// ---------------------------------------------------------------------------
__device__ __forceinline__ void stage_half(
    const bf16* __restrict__ src, bf16* dst, int grow0, int k0, int t)
{
  const int sr = t >> 3, lb = t & 7;
#pragma unroll
  for (int ch = 0; ch < 2; ch++) {
    int r    = ch * 64 + sr;                      // row within 128-row half
    int gcol = k0 + ((lb ^ (r & 7)) << 3);        // (tile_row&7)==(r&7)
    cp16(src + (size_t)(grow0 + r) * 1024 + gcol, dst + r * 64 + lb * 8);
  }
}

#define BAR()   __builtin_amdgcn_s_barrier()
#define LGKM0() { asm volatile("s_waitcnt lgkmcnt(0)" ::: "memory"); \
                  __builtin_amdgcn_sched_barrier(0); }
#define SB0()   __builtin_amdgcn_sched_barrier(0)

__global__ __launch_bounds__(512, 2) void score_8p(
    const bf16* __restrict__ A,    // enc_bf (32768 x 1024)
    const bf16* __restrict__ Bw,   // W1_bf (1024 x 1024)
    const bf16* __restrict__ u,    // (256 x 1024) bf16
    const float* __restrict__ Vw,  // (1024) f32
    float* __restrict__ e_part)    // (4 x 32768)
{
  __shared__ __align__(16) bf16 sA[2 * 16384];   // 64 KB (2 bufs x 256x64)
  __shared__ __align__(16) bf16 sB[2 * 16384];   // 64 KB
  __shared__ float s_part[4][256];               // 4 KB

  const int t = threadIdx.x;
  // XCD-chunked remap: 4 col-group blocks sharing an enc slab -> same XCD
  const int wg  = blockIdx.x;
  const int swz = (wg & 7) * 64 + (wg >> 3);
  const int bx  = swz & 3;
  const int by  = swz >> 2;
  const int row0 = by * 256;
  const int col0 = bx * 256;

  const int lane = t & 63, w = t >> 6;
  const int wm = w >> 2, wn = w & 3;          // 2M x 4N wave grid
  const int q = lane >> 4, c16 = lane & 15;

  // prologue: tile0 (A+B) and tile1 (B only; A1 staged at P1/P2 of kt=0)
  stage_half(A,  sA,          row0,       0,  t);  // A0 h0
  stage_half(A,  sA + 8192,   row0 + 128, 0,  t);  // A0 h1
  stage_half(Bw, sB,          col0,       0,  t);  // B0 h0
  stage_half(Bw, sB + 8192,   col0 + 128, 0,  t);  // B0 h1
  stage_half(Bw, sB + 16384,        col0,       64, t);  // B1 h0
  stage_half(Bw, sB + 16384 + 8192, col0 + 128, 64, t);  // B1 h1
  asm volatile("s_waitcnt vmcnt(4)" ::: "memory");  // tile0 ready; B1 in flight
  BAR(); SB0();

  f32x4 acc[8][4] = {};

  const int rb_base = wn * 64 + c16;
  const int ra_base = wm * 128 + c16;

  for (int kt = 0; kt < 16; ++kt) {
    const int cur = kt & 1;
    const bf16* As = sA + cur * 16384;
    const bf16* Bs = sB + cur * 16384;
    bf16* Anx = sA + (1 - cur) * 16384;   // dest for A(kt+1)
    bf16* Bnx = sB + cur * 16384;         // dest for B(kt+2)
    const bool stA = (kt < 15);
    const bool stB = (kt < 14);

    bf16x8 bfr0[4], bfr1[4], af[4];

    // ---------------- P1: kh0 (kq=q), i0-3 ----------------
#pragma unroll
    for (int j = 0; j < 4; j++) {
      const int rb = rb_base + j * 16;
      bfr0[j] = *(const bf16x8*)&Bs[rb * 64 + ((q ^ (rb & 7)) << 3)];
    }
#pragma unroll
    for (int i = 0; i < 4; i++) {
      const int ra = ra_base + i * 16;
      af[i] = *(const bf16x8*)&As[ra * 64 + ((q ^ (ra & 7)) << 3)];
    }
    if (stA) stage_half(A, Anx, row0, (kt + 1) * 64, t);
    BAR(); LGKM0();
    __builtin_amdgcn_s_setprio(1);
#pragma unroll
    for (int i = 0; i < 4; i++)
#pragma unroll
      for (int j = 0; j < 4; j++)
        acc[i][j] = __builtin_amdgcn_mfma_f32_16x16x32_bf16(af[i], bfr0[j], acc[i][j], 0, 0, 0);
    __builtin_amdgcn_s_setprio(0);
    BAR(); SB0();

    // ---------------- P2: kh1 (kq=4+q), i0-3 ----------------
#pragma unroll
    for (int j = 0; j < 4; j++) {
      const int rb = rb_base + j * 16;
      bfr1[j] = *(const bf16x8*)&Bs[rb * 64 + (((4 + q) ^ (rb & 7)) << 3)];
    }
#pragma unroll
    for (int i = 0; i < 4; i++) {
      const int ra = ra_base + i * 16;
      af[i] = *(const bf16x8*)&As[ra * 64 + (((4 + q) ^ (ra & 7)) << 3)];
    }
    if (stA) stage_half(A, Anx + 8192, row0 + 128, (kt + 1) * 64, t);
    BAR(); LGKM0();
    __builtin_amdgcn_s_setprio(1);
#pragma unroll
    for (int i = 0; i < 4; i++)
#pragma unroll
      for (int j = 0; j < 4; j++)
        acc[i][j] = __builtin_amdgcn_mfma_f32_16x16x32_bf16(af[i], bfr1[j], acc[i][j], 0, 0, 0);
    __builtin_amdgcn_s_setprio(0);
    BAR(); SB0();

    // ---------------- P3: kh0, i4-7 (bfr0 reused) ----------------
#pragma unroll
    for (int i = 0; i < 4; i++) {
      const int ra = ra_base + (i + 4) * 16;
      af[i] = *(const bf16x8*)&As[ra * 64 + ((q ^ (ra & 7)) << 3)];
    }
    if (stB) stage_half(Bw, Bnx, col0, (kt + 2) * 64, t);
    BAR(); LGKM0();
    __builtin_amdgcn_s_setprio(1);
#pragma unroll
    for (int i = 0; i < 4; i++)
#pragma unroll
      for (int j = 0; j < 4; j++)
        acc[i + 4][j] = __builtin_amdgcn_mfma_f32_16x16x32_bf16(af[i], bfr0[j], acc[i + 4][j], 0, 0, 0);
    __builtin_amdgcn_s_setprio(0);
    BAR(); SB0();

    // ---------------- P4: kh1, i4-7 (bfr1 reused) ----------------
#pragma unroll
    for (int i = 0; i < 4; i++) {
      const int ra = ra_base + (i + 4) * 16;
      af[i] = *(const bf16x8*)&As[ra * 64 + (((4 + q) ^ (ra & 7)) << 3)];
    }
    if (stB) stage_half(Bw, Bnx + 8192, col0 + 128, (kt + 2) * 64, t);
    BAR(); LGKM0();
    __builtin_amdgcn_s_setprio(1);
#pragma unroll
    for (int i = 0; i < 4; i++)
#pragma unroll
      for (int j = 0; j < 4; j++)
        acc[i + 4][j] = __builtin_amdgcn_mfma_f32_16x16x32_bf16(af[i], bfr1[j], acc[i + 4][j], 0, 0, 0);
    __builtin_amdgcn_s_setprio(0);
    // counted wait: leaves only B(kt+2)'s 4 loads in flight; guarantees
    // tile kt+1 (A staged P1/P2 of kt, B staged P3/P4 of kt-1) complete.
    if (kt < 14) { asm volatile("s_waitcnt vmcnt(4)" ::: "memory"); }
    else         { asm volatile("s_waitcnt vmcnt(0)" ::: "memory"); }
    BAR(); SB0();
  }

  // epilogue: rowsum_j tanh(acc + u[b])*Vw, reduce 16 lanes, then 4 wn-waves
  const int b = by * 2 + wm;
  float uc[4], vw[4];
#pragma unroll
  for (int j = 0; j < 4; j++) {
    const int gc = col0 + wn * 64 + j * 16 + c16;
    uc[j] = (float)u[b * 1024 + gc];
    vw[j] = Vw[gc];
  }
#pragma unroll
  for (int i = 0; i < 8; i++) {
#pragma unroll
    for (int r = 0; r < 4; r++) {
      float v = 0.0f;
#pragma unroll
      for (int j = 0; j < 4; j++)
        v += fast_tanh(acc[i][j][r] + uc[j]) * vw[j];
      v += __shfl_xor(v, 1);
      v += __shfl_xor(v, 2);
      v += __shfl_xor(v, 4);
      v += __shfl_xor(v, 8);
      if (c16 == 0) s_part[wn][wm * 128 + i * 16 + q * 4 + r] = v;
    }
  }
  __syncthreads();
  if (t < 256)
    e_part[(size_t)bx * 32768 + row0 + t] =
        s_part[0][t] + s_part[1][t] + s_part[2][t] + s_part[3][t];
}

// ---------------------------------------------------------------------------
// softmax + context + x_emb pack. grid 256 (one per b).
// ---------------------------------------------------------------------------
__global__ __launch_bounds__(256) void softmax_f(
    const float* __restrict__ e_part, // (4, 32768)
    const bf16* __restrict__ enc,     // enc_bf
    const float* __restrict__ xe4,    // (4,256,512)
    const float* __restrict__ o2eb,   // (512)
    float* __restrict__ attn_out,     // -> d_out section 3
    bf16* __restrict__ rnn_in)        // (256,1536)
{
  const int b = blockIdx.x;
  const int t = threadIdx.x;
  __shared__ float se[128];

  if (t < 128) {
    float s = 0.0f;
#pragma unroll
    for (int cb = 0; cb < 4; cb++) s += e_part[(size_t)cb * 32768 + b * 128 + t];
    se[t] = s;
  }
  __syncthreads();

  float m = -1e30f;
  for (int l = 0; l < 128; l++) m = fmaxf(m, se[l]);
  float sum = 0.0f;
  for (int l = 0; l < 128; l++) sum += expf(se[l] - m);
  float inv = 1.0f / sum;
  __syncthreads();
  if (t < 128) {
    float p = expf(se[t] - m) * inv;
    attn_out[b * 128 + t] = p;
    se[t] = p;
  }
  __syncthreads();

  // context: thread t handles 4 contiguous k of 1024
  float a0 = 0, a1 = 0, a2 = 0, a3 = 0;
  const bf16* ep = enc + (size_t)b * L_ * ENC_ + t * 4;
  for (int l = 0; l < 128; l++) {
    float p = se[l];
    bf16x4 v = *(const bf16x4*)(ep + (size_t)l * ENC_);
    a0 += p * (float)v[0]; a1 += p * (float)v[1];
    a2 += p * (float)v[2]; a3 += p * (float)v[3];
  }
  bf16x4 o;
  o[0] = (bf16)a0; o[1] = (bf16)a1; o[2] = (bf16)a2; o[3] = (bf16)a3;
  *(bf16x4*)(rnn_in + (size_t)b * 1536 + t * 4) = o;

  // x_emb pack: rnn_in[b][1024+j] = sum_z xe4[z][b][j] + o2e_b[j]
#pragma unroll
  for (int jj = 0; jj < 2; jj++) {
    int j = jj * 256 + t;
    float v = o2eb[j];
#pragma unroll
    for (int z = 0; z < 4; z++) v += xe4[(size_t)z * 131072 + b * 512 + j];
    rnn_in[(size_t)b * 1536 + 1024 + j] = (bf16)v;
  }
}

// ---------------------------------------------------------------------------
// Generic bf16 skinny GEMM (global_load_lds + swizzle). 64x64 tile, BK=64.
// ---------------------------------------------------------------------------
template <int ACT, int OUTF32>
__global__ __launch_bounds__(256) void gemm_f(
    const bf16* __restrict__ A, const bf16* __restrict__ Bw,
    const float* __restrict__ bias1,
    void* __restrict__ C, int K, int out_ld)
{
  __shared__ __align__(16) bf16 As[64 * 64];
  __shared__ __align__(16) bf16 Bs[64 * 64];

  const int t    = threadIdx.x;
  const int lane = t & 63;
  const int w    = t >> 6;
  const int q    = lane >> 4;
  const int c16  = lane & 15;
  const int sr   = t >> 3;
  const int lb   = t & 7;
  const int row0 = blockIdx.y * 64;
  const int col0 = blockIdx.x * 64;

  f32x4 acc[4] = {};

  for (int k0 = 0; k0 < K; k0 += 64) {
#pragma unroll
    for (int ch = 0; ch < 2; ch++) {
      int r    = ch * 32 + sr;
      int gcol = k0 + ((lb ^ (r & 7)) << 3);
      cp16(A  + (size_t)(row0 + r) * K + gcol, &As[ch * 2048 + t * 8]);
      cp16(Bw + (size_t)(col0 + r) * K + gcol, &Bs[ch * 2048 + t * 8]);
    }
    __syncthreads();
#pragma unroll
    for (int kkb = 0; kkb < 8; kkb += 4) {
      int rb = w * 16 + c16;
      bf16x8 bfr = *(const bf16x8*)&Bs[rb * 64 + (((kkb + q) ^ (rb & 7)) << 3)];
#pragma unroll
      for (int i = 0; i < 4; i++) {
        int ra = i * 16 + c16;
        bf16x8 af = *(const bf16x8*)&As[ra * 64 + (((kkb + q) ^ (ra & 7)) << 3)];
        acc[i] = __builtin_amdgcn_mfma_f32_16x16x32_bf16(af, bfr, acc[i], 0, 0, 0);
      }
    }
    __syncthreads();
  }

  const int gc = col0 + w * 16 + c16;
  float bias = bias1[gc];
#pragma unroll
  for (int i = 0; i < 4; i++) {
    int gr0 = row0 + i * 16 + q * 4;
#pragma unroll
    for (int r = 0; r < 4; r++) {
      float v = acc[i][r] + bias;
      if (ACT == 1) v = fast_tanh(v);
      size_t off = (size_t)(gr0 + r) * out_ld + gc;
      if (OUTF32) ((float*)C)[off] = v;
      else        ((bf16*)C)[off] = (bf16)v;
    }
  }
}

// ---------------------------------------------------------------------------
// GRU gates. 262144 threads. h0 f32 external.
// ---------------------------------------------------------------------------
__global__ __launch_bounds__(256) void gru_f(
    const bf16* __restrict__ gi, const bf16* __restrict__ gh,
    const float* __restrict__ h0,
    float* __restrict__ hnew_out, bf16* __restrict__ hnew_i)
{
  int idx = blockIdx.x * 256 + threadIdx.x;
  int b = idx >> 10, d = idx & 1023;
  const bf16* gib = gi + b * 3072;
  const bf16* ghb = gh + b * 3072;
  float ir = (float)gib[d], iz = (float)gib[1024 + d], in = (float)gib[2048 + d];
  float hr = (float)ghb[d], hz = (float)ghb[1024 + d], hn = (float)ghb[2048 + d];
  float r = fast_sigmoid(ir + hr);
  float z = fast_sigmoid(iz + hz);
  float n = fast_tanh(in + r * hn);
  float h = (1.0f - z) * n + z * h0[idx];
  hnew_out[idx] = h;
  hnew_i[idx]   = (bf16)h;
}

// ---------------------------------------------------------------------------
extern "C" void kernel_launch(void* const* d_in, const int* in_sizes, int n_in,
                              void* d_out, int out_size, void* d_ws, size_t ws_size,
                              hipStream_t stream) {
  const float* x      = (const float*)d_in[0];
  const float* hidden = (const float*)d_in[1];
  const float* enc    = (const float*)d_in[2];
  const float* W1_w   = (const float*)d_in[3];
  const float* W1_b   = (const float*)d_in[4];
  const float* W2_w   = (const float*)d_in[5];
  const float* W2_b   = (const float*)d_in[6];
  const float* V_w    = (const float*)d_in[7];
  // d_in[8] = V_b : softmax-invariant, unused
  const float* o2e_w  = (const float*)d_in[9];
  const float* o2e_b  = (const float*)d_in[10];
  const float* gru_wi = (const float*)d_in[11];
  const float* gru_wh = (const float*)d_in[12];
  const float* gru_bi = (const float*)d_in[13];
  const float* gru_bh = (const float*)d_in[14];
  const float* fc1_w  = (const float*)d_in[15];
  const float* fc1_b  = (const float*)d_in[16];
  const float* fc2_w  = (const float*)d_in[17];
  const float* fc2_b  = (const float*)d_in[18];

  float* out_main = (float*)d_out;                      // (256,4096)
  float* out_h    = out_main + (size_t)B_ * V_;         // (256,1024)
  float* out_attn = out_h + (size_t)B_ * DEC_;          // (256,128)

  // ws layout (bytes); NEED ~88 MB (ws_size >= ~103 MB measured in R5)
  char* ws = (char*)d_ws;
  bf16*  enc_bf  = (bf16*)(ws);                    // 64 MB
  bf16*  W1_bf   = (bf16*)(ws + 64 * MB_);         // 2 MB
  bf16*  wi_bf   = (bf16*)(ws + 66 * MB_);         // 9 MB
  bf16*  fc1_bf  = (bf16*)(ws + 75 * MB_);         // 1 MB
  bf16*  fc2_bf  = (bf16*)(ws + 76 * MB_);         // 4 MB
  bf16*  u_bf    = (bf16*)(ws + 80 * MB_);         // 512 KB
  bf16*  gh_bf   = (bf16*)(ws + 80 * MB_ + 524288);      // 1.5 MB
  float* e_part  = (float*)(ws + 82 * MB_);              // 512 KB
  bf16*  gi_bf   = (bf16*)(ws + 82 * MB_ + 524288);      // 1.5 MB
  bf16*  rnn_in  = (bf16*)(ws + 84 * MB_);               // 768 KB
  bf16*  tbuf    = (bf16*)(ws + 84 * MB_ + 786432);      // 256 KB
  bf16*  hnew_bf = (bf16*)(ws + 85 * MB_);               // 512 KB
  float* xe4     = (float*)(ws + 85 * MB_ + 524288);     // 2 MB

  // 1. setup: ugh + xemb GEMMs (blocks 0..383) overlapped with conversions
  setup_k<<<10624, 256, 0, stream>>>(
      hidden, W2_w, gru_wh, W1_b, W2_b, gru_bh, x, o2e_w,
      enc, W1_w, gru_wi, fc1_w, fc2_w,
      enc_bf, W1_bf, wi_bf, fc1_bf, fc2_bf, u_bf, gh_bf, xe4);

  // 2. score GEMM (256x256 tile, 4-phase interleaved pipeline) -> e_part
  score_8p<<<512, 512, 0, stream>>>(enc_bf, W1_bf, u_bf, V_w, e_part);

  // 3. softmax + context + x_emb pack
  softmax_f<<<B_, 256, 0, stream>>>(e_part, enc_bf, xe4, o2e_b, out_attn, rnn_in);

  // 4. gi = rnn_in @ wi^T + gru_bi (256x3072, K=1536)
  gemm_f<0, 0><<<dim3(48, 4), 256, 0, stream>>>(rnn_in, wi_bf, gru_bi, gi_bf, 1536, 3072);

  // 5. GRU gates -> h_new
  gru_f<<<(B_ * DEC_) / 256, 256, 0, stream>>>(gi_bf, gh_bf, hidden, out_h, hnew_bf);

  // 6. t = tanh(h_new @ fc1^T + fc1_b) (256x512, K=1024)
  gemm_f<1, 0><<<dim3(8, 4), 256, 0, stream>>>(hnew_bf, fc1_bf, fc1_b, tbuf, 1024, 512);

  // 7. out = t @ fc2^T + fc2_b (256x4096, K=512, f32 out)
  gemm_f<0, 1><<<dim3(64, 4), 256, 0, stream>>>(tbuf, fc2_bf, fc2_b, out_main, 512, 4096);
}